// Round 1
// baseline (502.604 us; speedup 1.0000x reference)
//
#include <hip/hip_runtime.h>

#define BATCH 65536
#define IN_DIM 128
#define INT_NODES 255
#define LEAF 256
#define OUT_DIM 8

// Wor [o][i][l] -> Wor_t [l][o][i] so each leaf's head is a contiguous 4KB slice.
__global__ __launch_bounds__(256) void transpose_wor(const float* __restrict__ Wor,
                                                     float* __restrict__ Wor_t) {
    int tid = blockIdx.x * 256 + threadIdx.x;       // 262144 total
    int l = tid >> 10;                              // /(8*128)
    int o = (tid >> 7) & 7;
    int i = tid & 127;
    Wor_t[tid] = Wor[(o * IN_DIM + i) * LEAF + l];
}

__global__ __launch_bounds__(256) void dgt_main(
    const float* __restrict__ x, const float* __restrict__ Wp,
    const float* __restrict__ bp, const float* __restrict__ Wor_t,
    const float* __restrict__ bor, const float* __restrict__ stds,
    float* __restrict__ out, float* __restrict__ stdo) {

    const int row = blockIdx.x * 256 + threadIdx.x;
    const float* xp = x + (size_t)row * IN_DIM;

    // x row -> registers (per-lane). 32x float4 loads.
    float xr[IN_DIM];
#pragma unroll
    for (int k = 0; k < IN_DIM; k += 4) {
        float4 v = *reinterpret_cast<const float4*>(xp + k);
        xr[k] = v.x; xr[k + 1] = v.y; xr[k + 2] = v.z; xr[k + 3] = v.w;
    }

    float abs_sum = 0.f;
    int node = 0;  // heap index; after 8 updates lands in [255,510]

    for (int j = 0; j < INT_NODES; ++j) {
        const float* w = Wp + j * IN_DIM;   // wave-uniform -> s_load stream
        float a0 = 0.f, a1 = 0.f, a2 = 0.f, a3 = 0.f;
#pragma unroll
        for (int k = 0; k < IN_DIM; k += 4) {
            a0 = fmaf(w[k + 0], xr[k + 0], a0);
            a1 = fmaf(w[k + 1], xr[k + 1], a1);
            a2 = fmaf(w[k + 2], xr[k + 2], a2);
            a3 = fmaf(w[k + 3], xr[k + 3], a3);
        }
        float z = ((a0 + a1) + (a2 + a3)) + bp[j];
        abs_sum += fabsf(z);

        // Hard routing: this lane is "at" node j once per level.
        if (j == node) {
            float zs = z;
            // Sign is discontinuous in the output: if too close to 0, resolve
            // the sign in fp64 so summation-order noise can't flip the leaf.
            if (fabsf(z) < 2e-4f) {
                double zd = (double)bp[j];
#pragma unroll
                for (int k = 0; k < IN_DIM; ++k)
                    zd = fma((double)w[k], (double)xr[k], zd);
                zs = (zd < 0.0) ? -1.f : 1.f;
            }
            node = 2 * node + 1 + (zs < 0.f ? 1 : 0);  // z>=0 -> left child
        }
    }

    const float fac = abs_sum * (1.0f / (float)INT_NODES);
    // p* = softmax prob of the argmax leaf. Closed form:
    // sum_l exp(and_z_l - 8 fac) = (1 + exp(-2 fac))^8  (tree recursion).
    const float t = expf(-2.0f * fac);
    const float q = 1.0f + t;
    const float q2 = q * q, q4 = q2 * q2, q8 = q4 * q4;
    const float pstar = 1.0f / q8;

    const int leaf = node - INT_NODES;
    const float* wl = Wor_t + (size_t)leaf * (OUT_DIM * IN_DIM);  // contiguous 4KB

    float outv[OUT_DIM];
#pragma unroll
    for (int o = 0; o < OUT_DIM; ++o) {
        const float* wo = wl + o * IN_DIM;       // per-lane gather (contiguous)
        const float* bo = bor + o * IN_DIM;      // wave-uniform -> s_load
        float s0 = 0.f, s1 = 0.f, s2 = 0.f, s3 = 0.f;
        float b0 = 0.f, b1 = 0.f, b2 = 0.f, b3 = 0.f;
#pragma unroll
        for (int k = 0; k < IN_DIM; k += 4) {
            float4 wv = *reinterpret_cast<const float4*>(wo + k);
            s0 = fmaf(wv.x, xr[k + 0], s0);
            s1 = fmaf(wv.y, xr[k + 1], s1);
            s2 = fmaf(wv.z, xr[k + 2], s2);
            s3 = fmaf(wv.w, xr[k + 3], s3);
            b0 = fmaf(bo[k + 0], xr[k + 0], b0);
            b1 = fmaf(bo[k + 1], xr[k + 1], b1);
            b2 = fmaf(bo[k + 2], xr[k + 2], b2);
            b3 = fmaf(bo[k + 3], xr[k + 3], b3);
        }
        outv[o] = pstar * ((s0 + s1) + (s2 + s3)) + ((b0 + b1) + (b2 + b3));
    }

    float4* op = reinterpret_cast<float4*>(out + (size_t)row * OUT_DIM);
    op[0] = make_float4(outv[0], outv[1], outv[2], outv[3]);
    op[1] = make_float4(outv[4], outv[5], outv[6], outv[7]);

    const float* sl = stds + (size_t)leaf * OUT_DIM;  // [256][8] layout
    float sv[OUT_DIM];
#pragma unroll
    for (int o = 0; o < OUT_DIM; ++o) {
        float v = pstar * sl[o];
        sv[o] = fminf(fmaxf(v, -20.0f), 2.0f);
    }
    float4* sp = reinterpret_cast<float4*>(stdo + (size_t)row * OUT_DIM);
    sp[0] = make_float4(sv[0], sv[1], sv[2], sv[3]);
    sp[1] = make_float4(sv[4], sv[5], sv[6], sv[7]);
}

extern "C" void kernel_launch(void* const* d_in, const int* in_sizes, int n_in,
                              void* d_out, int out_size, void* d_ws, size_t ws_size,
                              hipStream_t stream) {
    const float* x    = (const float*)d_in[0];
    const float* Wp   = (const float*)d_in[1];
    const float* bp   = (const float*)d_in[2];
    // d_in[3] = Wand (fixed +-1 routing) -- folded into the traversal, unused.
    const float* Wor  = (const float*)d_in[4];
    const float* bor  = (const float*)d_in[5];
    const float* stds = (const float*)d_in[6];
    float* out = (float*)d_out;
    float* wor_t = (float*)d_ws;   // 1 MB scratch: Wor transposed [l][o][i]

    transpose_wor<<<(LEAF * OUT_DIM * IN_DIM) / 256, 256, 0, stream>>>(Wor, wor_t);
    dgt_main<<<BATCH / 256, 256, 0, stream>>>(x, Wp, bp, wor_t, bor, stds,
                                              out, out + (size_t)BATCH * OUT_DIM);
}

// Round 2
// 501.431 us; speedup vs baseline: 1.0023x; 1.0023x over previous
//
#include <hip/hip_runtime.h>

#define BATCH 65536
#define IN_DIM 128
#define INT_NODES 255
#define LEAF 256
#define OUT_DIM 8

// Wor [o][i][l] -> Wor_t [l][o][i] so each leaf's head is a contiguous 4KB slice.
__global__ __launch_bounds__(256) void transpose_wor(const float* __restrict__ Wor,
                                                     float* __restrict__ Wor_t) {
    int tid = blockIdx.x * 256 + threadIdx.x;       // 262144 total
    int l = tid >> 10;                              // /(8*128)
    int o = (tid >> 7) & 7;
    int i = tid & 127;
    Wor_t[tid] = Wor[(o * IN_DIM + i) * LEAF + l];
}

__global__ __launch_bounds__(256) void dgt_main(
    const float* __restrict__ x, const float* __restrict__ Wp,
    const float* __restrict__ bp, const float* __restrict__ Wor_t,
    const float* __restrict__ bor, const float* __restrict__ stds,
    float* __restrict__ out, float* __restrict__ stdo) {

    const int row = blockIdx.x * 256 + threadIdx.x;
    const float* xp = x + (size_t)row * IN_DIM;

    // x row -> registers (per-lane). 32x float4 loads. 128 VGPRs -- the big
    // fixed cost; everything else must stay small to avoid spills (R1 hit the
    // 256-VGPR cap and spilled).
    float xr[IN_DIM];
#pragma unroll
    for (int k = 0; k < IN_DIM; k += 4) {
        float4 v = *reinterpret_cast<const float4*>(xp + k);
        xr[k] = v.x; xr[k + 1] = v.y; xr[k + 2] = v.z; xr[k + 3] = v.w;
    }

    float abs_sum = 0.f;
    int node = 0;  // heap index; after 8 updates lands in [255,510]

    // Per node: K-loop in 16-float chunks so only ~16-32 w values are live at
    // once; the unrolled chunks let loads of chunk c+1 overlap FMAs of chunk c.
    for (int j = 0; j < INT_NODES; ++j) {
        const float* w = Wp + j * IN_DIM;   // wave-uniform address
        float a0 = 0.f, a1 = 0.f, a2 = 0.f, a3 = 0.f;
#pragma unroll
        for (int c = 0; c < IN_DIM; c += 16) {
            float4 w0 = *reinterpret_cast<const float4*>(w + c);
            float4 w1 = *reinterpret_cast<const float4*>(w + c + 4);
            float4 w2 = *reinterpret_cast<const float4*>(w + c + 8);
            float4 w3 = *reinterpret_cast<const float4*>(w + c + 12);
            a0 = fmaf(w0.x, xr[c + 0], a0);  a1 = fmaf(w0.y, xr[c + 1], a1);
            a2 = fmaf(w0.z, xr[c + 2], a2);  a3 = fmaf(w0.w, xr[c + 3], a3);
            a0 = fmaf(w1.x, xr[c + 4], a0);  a1 = fmaf(w1.y, xr[c + 5], a1);
            a2 = fmaf(w1.z, xr[c + 6], a2);  a3 = fmaf(w1.w, xr[c + 7], a3);
            a0 = fmaf(w2.x, xr[c + 8], a0);  a1 = fmaf(w2.y, xr[c + 9], a1);
            a2 = fmaf(w2.z, xr[c +10], a2);  a3 = fmaf(w2.w, xr[c +11], a3);
            a0 = fmaf(w3.x, xr[c +12], a0);  a1 = fmaf(w3.y, xr[c +13], a1);
            a2 = fmaf(w3.z, xr[c +14], a2);  a3 = fmaf(w3.w, xr[c +15], a3);
        }
        float z = ((a0 + a1) + (a2 + a3)) + bp[j];
        abs_sum += fabsf(z);

        if (j == node) {
            float zs = z;
            // Sign is discontinuous in the output: resolve near-zero z in fp64
            // so fp32 summation-order noise can't flip the leaf choice.
            if (fabsf(z) < 2e-4f) {
                double zd = (double)bp[j];
                for (int k = 0; k < IN_DIM; ++k)
                    zd = fma((double)w[k], (double)xr[k], zd);
                zs = (zd < 0.0) ? -1.f : 1.f;
            }
            node = 2 * node + 1 + (zs < 0.f ? 1 : 0);  // z>=0 -> left child
        }
    }

    const float fac = abs_sum * (1.0f / (float)INT_NODES);
    // p* = softmax prob of the argmax leaf. Closed form:
    // sum_l exp(and_z_l - 8 fac) = (1 + exp(-2 fac))^8  (tree recursion).
    const float t = expf(-2.0f * fac);
    const float q = 1.0f + t;
    const float q2 = q * q, q4 = q2 * q2, q8 = q4 * q4;
    const float pstar = 1.0f / q8;

    const int leaf = node - INT_NODES;
    const float* wl = Wor_t + (size_t)leaf * (OUT_DIM * IN_DIM);  // contiguous 4KB

    float outv[OUT_DIM];
#pragma unroll
    for (int o = 0; o < OUT_DIM; ++o) {
        const float* wo = wl + o * IN_DIM;       // per-lane gather (contiguous)
        const float* bo = bor + o * IN_DIM;      // wave-uniform
        float s0 = 0.f, s1 = 0.f, s2 = 0.f, s3 = 0.f;
        float b0 = 0.f, b1 = 0.f, b2 = 0.f, b3 = 0.f;
#pragma unroll
        for (int k = 0; k < IN_DIM; k += 4) {
            float4 wv = *reinterpret_cast<const float4*>(wo + k);
            s0 = fmaf(wv.x, xr[k + 0], s0);
            s1 = fmaf(wv.y, xr[k + 1], s1);
            s2 = fmaf(wv.z, xr[k + 2], s2);
            s3 = fmaf(wv.w, xr[k + 3], s3);
            b0 = fmaf(bo[k + 0], xr[k + 0], b0);
            b1 = fmaf(bo[k + 1], xr[k + 1], b1);
            b2 = fmaf(bo[k + 2], xr[k + 2], b2);
            b3 = fmaf(bo[k + 3], xr[k + 3], b3);
        }
        outv[o] = pstar * ((s0 + s1) + (s2 + s3)) + ((b0 + b1) + (b2 + b3));
    }

    float4* op = reinterpret_cast<float4*>(out + (size_t)row * OUT_DIM);
    op[0] = make_float4(outv[0], outv[1], outv[2], outv[3]);
    op[1] = make_float4(outv[4], outv[5], outv[6], outv[7]);

    const float* sl = stds + (size_t)leaf * OUT_DIM;  // [256][8] layout
    float sv[OUT_DIM];
#pragma unroll
    for (int o = 0; o < OUT_DIM; ++o) {
        float v = pstar * sl[o];
        sv[o] = fminf(fmaxf(v, -20.0f), 2.0f);
    }
    float4* sp = reinterpret_cast<float4*>(stdo + (size_t)row * OUT_DIM);
    sp[0] = make_float4(sv[0], sv[1], sv[2], sv[3]);
    sp[1] = make_float4(sv[4], sv[5], sv[6], sv[7]);
}

extern "C" void kernel_launch(void* const* d_in, const int* in_sizes, int n_in,
                              void* d_out, int out_size, void* d_ws, size_t ws_size,
                              hipStream_t stream) {
    const float* x    = (const float*)d_in[0];
    const float* Wp   = (const float*)d_in[1];
    const float* bp   = (const float*)d_in[2];
    // d_in[3] = Wand (fixed +-1 routing) -- folded into the traversal, unused.
    const float* Wor  = (const float*)d_in[4];
    const float* bor  = (const float*)d_in[5];
    const float* stds = (const float*)d_in[6];
    float* out = (float*)d_out;
    float* wor_t = (float*)d_ws;   // 1 MB scratch: Wor transposed [l][o][i]

    transpose_wor<<<(LEAF * OUT_DIM * IN_DIM) / 256, 256, 0, stream>>>(Wor, wor_t);
    dgt_main<<<BATCH / 256, 256, 0, stream>>>(x, Wp, bp, wor_t, bor, stds,
                                              out, out + (size_t)BATCH * OUT_DIM);
}

// Round 3
// 406.556 us; speedup vs baseline: 1.2362x; 1.2334x over previous
//
#include <hip/hip_runtime.h>

#define BATCH 65536
#define IN_DIM 128
#define INT_NODES 255
#define LEAF 256
#define OUT_DIM 8

// Wor [o][i][l] -> Wor_t [l][o][i] so each leaf's head is a contiguous 4KB slice.
__global__ __launch_bounds__(256) void transpose_wor(const float* __restrict__ Wor,
                                                     float* __restrict__ Wor_t) {
    int tid = blockIdx.x * 256 + threadIdx.x;       // 262144 total
    int l = tid >> 10;                              // /(8*128)
    int o = (tid >> 7) & 7;
    int i = tid & 127;
    Wor_t[tid] = Wor[(o * IN_DIM + i) * LEAF + l];
}

__global__ __launch_bounds__(256) void dgt_main(
    const float* __restrict__ x, const float* __restrict__ Wp,
    const float* __restrict__ bp, const float* __restrict__ Wor_t,
    const float* __restrict__ bor, const float* __restrict__ stds,
    float* __restrict__ out, float* __restrict__ stdo) {

    const int row = blockIdx.x * 256 + threadIdx.x;
    const float* xp = x + (size_t)row * IN_DIM;

    // x row -> registers. CRITICAL: xr must NEVER be dynamically indexed --
    // R1/R2 had a dynamic index in the fp64 rescue loop, which demoted the
    // whole array to scratch and made every FMA a scratch read (500 us).
    float xr[IN_DIM];
#pragma unroll
    for (int k = 0; k < IN_DIM; k += 4) {
        float4 v = *reinterpret_cast<const float4*>(xp + k);
        xr[k] = v.x; xr[k + 1] = v.y; xr[k + 2] = v.z; xr[k + 3] = v.w;
    }

    float abs_sum = 0.f;
    int node = 0;  // heap index; after 8 updates lands in [255,510]

    for (int j = 0; j < INT_NODES; ++j) {
        const float* w = Wp + j * IN_DIM;   // wave-uniform -> scalar loads
        float a0 = 0.f, a1 = 0.f, a2 = 0.f, a3 = 0.f;
#pragma unroll
        for (int c = 0; c < IN_DIM; c += 16) {
            float4 w0 = *reinterpret_cast<const float4*>(w + c);
            float4 w1 = *reinterpret_cast<const float4*>(w + c + 4);
            float4 w2 = *reinterpret_cast<const float4*>(w + c + 8);
            float4 w3 = *reinterpret_cast<const float4*>(w + c + 12);
            a0 = fmaf(w0.x, xr[c + 0], a0);  a1 = fmaf(w0.y, xr[c + 1], a1);
            a2 = fmaf(w0.z, xr[c + 2], a2);  a3 = fmaf(w0.w, xr[c + 3], a3);
            a0 = fmaf(w1.x, xr[c + 4], a0);  a1 = fmaf(w1.y, xr[c + 5], a1);
            a2 = fmaf(w1.z, xr[c + 6], a2);  a3 = fmaf(w1.w, xr[c + 7], a3);
            a0 = fmaf(w2.x, xr[c + 8], a0);  a1 = fmaf(w2.y, xr[c + 9], a1);
            a2 = fmaf(w2.z, xr[c +10], a2);  a3 = fmaf(w2.w, xr[c +11], a3);
            a0 = fmaf(w3.x, xr[c +12], a0);  a1 = fmaf(w3.y, xr[c +13], a1);
            a2 = fmaf(w3.z, xr[c +14], a2);  a3 = fmaf(w3.w, xr[c +15], a3);
        }
        float z = ((a0 + a1) + (a2 + a3)) + bp[j];
        abs_sum += fabsf(z);

        // Branchless traversal update (hot path). Rescue of near-zero z is
        // pulled out below the predicated update and reads x from GLOBAL
        // memory (xp), never xr, so xr stays in registers.
        bool at_node = (j == node);
        bool ambiguous = at_node && (fabsf(z) < 2e-4f);
        float zs = z;
        if (ambiguous) {                     // exec-masked, ~0.1% of lanes
            double zd = (double)bp[j];
            for (int k = 0; k < IN_DIM; ++k)
                zd = fma((double)w[k], (double)xp[k], zd);
            zs = (zd < 0.0) ? -1.f : 1.f;
        }
        int next = 2 * node + 1 + (zs < 0.f ? 1 : 0);
        node = at_node ? next : node;
    }

    const float fac = abs_sum * (1.0f / (float)INT_NODES);
    // p* = softmax prob of the argmax leaf. Closed form:
    // sum_l exp(and_z_l - 8 fac) = (1 + exp(-2 fac))^8  (tree recursion).
    const float t = expf(-2.0f * fac);
    const float q = 1.0f + t;
    const float q2 = q * q, q4 = q2 * q2, q8 = q4 * q4;
    const float pstar = 1.0f / q8;

    const int leaf = node - INT_NODES;
    const float* wl = Wor_t + (size_t)leaf * (OUT_DIM * IN_DIM);  // contiguous 4KB

    float outv[OUT_DIM];
#pragma unroll
    for (int o = 0; o < OUT_DIM; ++o) {
        const float* wo = wl + o * IN_DIM;       // per-lane gather (contiguous)
        const float* bo = bor + o * IN_DIM;      // wave-uniform
        float s0 = 0.f, s1 = 0.f, s2 = 0.f, s3 = 0.f;
        float b0 = 0.f, b1 = 0.f, b2 = 0.f, b3 = 0.f;
#pragma unroll
        for (int k = 0; k < IN_DIM; k += 4) {
            float4 wv = *reinterpret_cast<const float4*>(wo + k);
            s0 = fmaf(wv.x, xr[k + 0], s0);
            s1 = fmaf(wv.y, xr[k + 1], s1);
            s2 = fmaf(wv.z, xr[k + 2], s2);
            s3 = fmaf(wv.w, xr[k + 3], s3);
            b0 = fmaf(bo[k + 0], xr[k + 0], b0);
            b1 = fmaf(bo[k + 1], xr[k + 1], b1);
            b2 = fmaf(bo[k + 2], xr[k + 2], b2);
            b3 = fmaf(bo[k + 3], xr[k + 3], b3);
        }
        outv[o] = pstar * ((s0 + s1) + (s2 + s3)) + ((b0 + b1) + (b2 + b3));
    }

    float4* op = reinterpret_cast<float4*>(out + (size_t)row * OUT_DIM);
    op[0] = make_float4(outv[0], outv[1], outv[2], outv[3]);
    op[1] = make_float4(outv[4], outv[5], outv[6], outv[7]);

    const float* sl = stds + (size_t)leaf * OUT_DIM;  // [256][8] layout
    float sv[OUT_DIM];
#pragma unroll
    for (int o = 0; o < OUT_DIM; ++o) {
        float v = pstar * sl[o];
        sv[o] = fminf(fmaxf(v, -20.0f), 2.0f);
    }
    float4* sp = reinterpret_cast<float4*>(stdo + (size_t)row * OUT_DIM);
    sp[0] = make_float4(sv[0], sv[1], sv[2], sv[3]);
    sp[1] = make_float4(sv[4], sv[5], sv[6], sv[7]);
}

extern "C" void kernel_launch(void* const* d_in, const int* in_sizes, int n_in,
                              void* d_out, int out_size, void* d_ws, size_t ws_size,
                              hipStream_t stream) {
    const float* x    = (const float*)d_in[0];
    const float* Wp   = (const float*)d_in[1];
    const float* bp   = (const float*)d_in[2];
    // d_in[3] = Wand (fixed +-1 routing) -- folded into the traversal, unused.
    const float* Wor  = (const float*)d_in[4];
    const float* bor  = (const float*)d_in[5];
    const float* stds = (const float*)d_in[6];
    float* out = (float*)d_out;
    float* wor_t = (float*)d_ws;   // 1 MB scratch: Wor transposed [l][o][i]

    transpose_wor<<<(LEAF * OUT_DIM * IN_DIM) / 256, 256, 0, stream>>>(Wor, wor_t);
    dgt_main<<<BATCH / 256, 256, 0, stream>>>(x, Wp, bp, wor_t, bor, stds,
                                              out, out + (size_t)BATCH * OUT_DIM);
}

// Round 4
// 397.901 us; speedup vs baseline: 1.2631x; 1.0218x over previous
//
#include <hip/hip_runtime.h>

#define BATCH 65536
#define IN_DIM 128
#define INT_NODES 255
#define LEAF 256
#define OUT_DIM 8
#define ROWS_PB 64     // rows per block (one per lane)
#define SEG 32         // K elements per wave (4 waves cover 128)
#define TILE 16        // nodes per LDS tile
#define NTILES 16      // ceil(255/16)

// Wor [o][i][l] -> Wor_t [l][o][i] so each leaf's head is a contiguous 4KB slice.
__global__ __launch_bounds__(256) void transpose_wor(const float* __restrict__ Wor,
                                                     float* __restrict__ Wor_t) {
    int tid = blockIdx.x * 256 + threadIdx.x;       // 262144 total
    int l = tid >> 10;
    int o = (tid >> 7) & 7;
    int i = tid & 127;
    Wor_t[tid] = Wor[(o * IN_DIM + i) * LEAF + l];
}

__global__ __launch_bounds__(256) void dgt_main(
    const float* __restrict__ x, const float* __restrict__ Wp,
    const float* __restrict__ bp, const float* __restrict__ Wor_t,
    const float* __restrict__ bor, const float* __restrict__ stds,
    float* __restrict__ out, float* __restrict__ stdo) {

    // LDS: zbuf (32 KB, double-buffered partial-z tiles) aliased by the heads
    // reduction buffer (16 KB) which is only live after zbuf[0] is dead.
    __shared__ union {
        float z[2][TILE][4][64];   // [buf][node-in-tile][wave][row-lane]
        float o[2][8][4][64];      // [s|b][out][wave][row-lane]
    } sb;
    __shared__ int   leafbuf[64];
    __shared__ float psbuf[64];

    const int tid  = threadIdx.x;
    const int wave = tid >> 6;        // 0..3 -> K segment
    const int lane = tid & 63;        // row within block
    const int rowbase = blockIdx.x * ROWS_PB;
    const int row = rowbase + lane;
    const int seg = wave * SEG;

    // x segment -> registers (8x float4). Never dynamically indexed.
    const float* xp = x + (size_t)row * IN_DIM + seg;
    float xr[SEG];
#pragma unroll
    for (int k = 0; k < SEG; k += 4) {
        float4 v = *reinterpret_cast<const float4*>(xp + k);
        xr[k] = v.x; xr[k + 1] = v.y; xr[k + 2] = v.z; xr[k + 3] = v.w;
    }

    float abs_sum = 0.f;   // only wave0's copy is meaningful
    int   node = 0;

    for (int t = 0; t < NTILES; ++t) {
        const int jbase = t * TILE;
        const int cnt = (jbase + TILE <= INT_NODES) ? TILE : (INT_NODES - jbase);
        // ---- partial dot products for this tile (all waves) ----
        for (int jj = 0; jj < cnt; ++jj) {
            const float* w = Wp + (jbase + jj) * IN_DIM + seg;  // wave-uniform, 128 B
            float a0 = 0.f, a1 = 0.f, a2 = 0.f, a3 = 0.f;
#pragma unroll
            for (int c = 0; c < SEG; c += 4) {
                float4 wv = *reinterpret_cast<const float4*>(w + c);
                a0 = fmaf(wv.x, xr[c + 0], a0);
                a1 = fmaf(wv.y, xr[c + 1], a1);
                a2 = fmaf(wv.z, xr[c + 2], a2);
                a3 = fmaf(wv.w, xr[c + 3], a3);
            }
            sb.z[t & 1][jj][wave][lane] = (a0 + a1) + (a2 + a3);
        }
        // ---- wave0 combines the PREVIOUS tile while others run ahead ----
        if (wave == 0 && t > 0) {
            const int pb = (t - 1) * TILE;
            const int pc = TILE;  // previous tile is always full here
            for (int jj = 0; jj < pc; ++jj) {
                const int j = pb + jj;
                float z = sb.z[(t - 1) & 1][jj][0][lane] + sb.z[(t - 1) & 1][jj][1][lane]
                        + sb.z[(t - 1) & 1][jj][2][lane] + sb.z[(t - 1) & 1][jj][3][lane];
                z += bp[j];
                abs_sum += fabsf(z);
                bool at = (j == node);
                float zs = z;
                if (at && fabsf(z) < 2e-4f) {     // rare: exact sign via fp64
                    double zd = (double)bp[j];
                    const float* wr = Wp + j * IN_DIM;
                    const float* xrow = x + (size_t)row * IN_DIM;
                    for (int k = 0; k < IN_DIM; ++k)
                        zd = fma((double)wr[k], (double)xrow[k], zd);
                    zs = (zd < 0.0) ? -1.f : 1.f;
                }
                int nxt = 2 * node + 1 + (zs < 0.f ? 1 : 0);
                node = at ? nxt : node;
            }
        }
        __syncthreads();
    }

    if (wave == 0) {
        // final tile (15 nodes) + closing math
        const int pb = (NTILES - 1) * TILE;
        const int pc = INT_NODES - pb;
        for (int jj = 0; jj < pc; ++jj) {
            const int j = pb + jj;
            float z = sb.z[(NTILES - 1) & 1][jj][0][lane] + sb.z[(NTILES - 1) & 1][jj][1][lane]
                    + sb.z[(NTILES - 1) & 1][jj][2][lane] + sb.z[(NTILES - 1) & 1][jj][3][lane];
            z += bp[j];
            abs_sum += fabsf(z);
            bool at = (j == node);
            float zs = z;
            if (at && fabsf(z) < 2e-4f) {
                double zd = (double)bp[j];
                const float* wr = Wp + j * IN_DIM;
                const float* xrow = x + (size_t)row * IN_DIM;
                for (int k = 0; k < IN_DIM; ++k)
                    zd = fma((double)wr[k], (double)xrow[k], zd);
                zs = (zd < 0.0) ? -1.f : 1.f;
            }
            int nxt = 2 * node + 1 + (zs < 0.f ? 1 : 0);
            node = at ? nxt : node;
        }
        const float fac = abs_sum * (1.0f / (float)INT_NODES);
        // p* of the argmax leaf: sum_l exp(and_z_l - 8 fac) = (1+e^{-2fac})^8.
        const float e = expf(-2.0f * fac);
        const float q = 1.0f + e;
        const float q2 = q * q, q4 = q2 * q2, q8 = q4 * q4;
        leafbuf[lane] = node - INT_NODES;
        psbuf[lane] = 1.0f / q8;
    }
    __syncthreads();

    // ---- heads, K-split: each wave does its 32-elem segment ----
    {
        const int leaf = leafbuf[lane];
        const float* wl = Wor_t + (size_t)leaf * (OUT_DIM * IN_DIM) + seg;
        const float* bb = bor + seg;
#pragma unroll
        for (int o = 0; o < OUT_DIM; ++o) {
            const float* wo = wl + o * IN_DIM;   // per-lane (leaf differs)
            const float* bo = bb + o * IN_DIM;   // wave-uniform
            float s0 = 0.f, s1 = 0.f, s2 = 0.f, s3 = 0.f;
            float b0 = 0.f, b1 = 0.f, b2 = 0.f, b3 = 0.f;
#pragma unroll
            for (int c = 0; c < SEG; c += 4) {
                float4 wv = *reinterpret_cast<const float4*>(wo + c);
                s0 = fmaf(wv.x, xr[c + 0], s0);
                s1 = fmaf(wv.y, xr[c + 1], s1);
                s2 = fmaf(wv.z, xr[c + 2], s2);
                s3 = fmaf(wv.w, xr[c + 3], s3);
                b0 = fmaf(bo[c + 0], xr[c + 0], b0);
                b1 = fmaf(bo[c + 1], xr[c + 1], b1);
                b2 = fmaf(bo[c + 2], xr[c + 2], b2);
                b3 = fmaf(bo[c + 3], xr[c + 3], b3);
            }
            sb.o[0][o][wave][lane] = (s0 + s1) + (s2 + s3);
            sb.o[1][o][wave][lane] = (b0 + b1) + (b2 + b3);
        }
    }
    __syncthreads();

    // ---- final reduce + stores: 256 threads x 2 outputs each ----
    {
        const int r = tid & 63;
        const int og = tid >> 6;           // 0..3 -> outputs {2og, 2og+1}
        const float ps = psbuf[r];
        const int lf = leafbuf[r];
#pragma unroll
        for (int u = 0; u < 2; ++u) {
            const int o = og * 2 + u;
            float s = sb.o[0][o][0][r] + sb.o[0][o][1][r]
                    + sb.o[0][o][2][r] + sb.o[0][o][3][r];
            float b = sb.o[1][o][0][r] + sb.o[1][o][1][r]
                    + sb.o[1][o][2][r] + sb.o[1][o][3][r];
            out[(size_t)(rowbase + r) * OUT_DIM + o] = ps * s + b;
            float sd = ps * stds[lf * OUT_DIM + o];
            stdo[(size_t)(rowbase + r) * OUT_DIM + o] = fminf(fmaxf(sd, -20.0f), 2.0f);
        }
    }
}

extern "C" void kernel_launch(void* const* d_in, const int* in_sizes, int n_in,
                              void* d_out, int out_size, void* d_ws, size_t ws_size,
                              hipStream_t stream) {
    const float* x    = (const float*)d_in[0];
    const float* Wp   = (const float*)d_in[1];
    const float* bp   = (const float*)d_in[2];
    // d_in[3] = Wand (fixed +-1 routing) -- folded into the traversal, unused.
    const float* Wor  = (const float*)d_in[4];
    const float* bor  = (const float*)d_in[5];
    const float* stds = (const float*)d_in[6];
    float* out = (float*)d_out;
    float* wor_t = (float*)d_ws;   // 1 MB scratch: Wor transposed [l][o][i]

    transpose_wor<<<(LEAF * OUT_DIM * IN_DIM) / 256, 256, 0, stream>>>(Wor, wor_t);
    dgt_main<<<BATCH / ROWS_PB, 256, 0, stream>>>(x, Wp, bp, wor_t, bor, stds,
                                                  out, out + (size_t)BATCH * OUT_DIM);
}

// Round 5
// 155.097 us; speedup vs baseline: 3.2406x; 2.5655x over previous
//
#include <hip/hip_runtime.h>

#define BATCH 65536
#define IN_DIM 128
#define INT_NODES 255
#define LEAF 256
#define OUT_DIM 8
#define ROWS_PB 64
#define NBLK (BATCH / ROWS_PB)   // 1024

typedef float  f4v __attribute__((ext_vector_type(4)));
typedef short  s8v __attribute__((ext_vector_type(8)));

__device__ __forceinline__ unsigned short bfhi(float f) {
    unsigned u = __builtin_bit_cast(unsigned, f);
    unsigned r = (u + 0x7FFFu + ((u >> 16) & 1u)) >> 16;   // RNE
    return (unsigned short)r;
}
__device__ __forceinline__ float bf2f(unsigned short h) {
    unsigned u = ((unsigned)h) << 16;
    return __builtin_bit_cast(float, u);
}

// Wor [o][i][l] -> Wor_t [l][o][i] so each leaf's head is a contiguous 4KB slice.
__global__ __launch_bounds__(256) void transpose_wor(const float* __restrict__ Wor,
                                                     float* __restrict__ Wor_t) {
    int tid = blockIdx.x * 256 + threadIdx.x;
    int l = tid >> 10;
    int o = (tid >> 7) & 7;
    int i = tid & 127;
    Wor_t[tid] = Wor[(o * IN_DIM + i) * LEAF + l];
}

// Pack Wp into MFMA B-operand fragments (bf16 hi/lo split), node 255 zero-pad.
// Fragment def (16x16x32): B[k = ks*32 + (lane>>4)*8 + j][n = ntg*16 + (lane&15)].
// Storage slot = ((ks*16 + ntg)*64 + lane)*8 + j.
__global__ __launch_bounds__(256) void build_bfrag(const float* __restrict__ Wp,
                                                   unsigned short* __restrict__ Bh,
                                                   unsigned short* __restrict__ Bl) {
    int slot = blockIdx.x * 256 + threadIdx.x;   // 32768 total (grid 128)
    int j    = slot & 7;
    int lane = (slot >> 3) & 63;
    int ntg  = (slot >> 9) & 15;
    int ks   = slot >> 13;
    int n = ntg * 16 + (lane & 15);
    int k = ks * 32 + (lane >> 4) * 8 + j;
    float v = (n < INT_NODES) ? Wp[n * IN_DIM + k] : 0.f;
    unsigned short h = bfhi(v);
    Bh[slot] = h;
    Bl[slot] = bfhi(v - bf2f(h));
}

__global__ __launch_bounds__(256) void dgt_main(
    const float* __restrict__ x, const float* __restrict__ Wp,
    const float* __restrict__ bp, const unsigned short* __restrict__ Bhg,
    const unsigned short* __restrict__ Blg, const float* __restrict__ Wor_t,
    const float* __restrict__ bor, const float* __restrict__ stds,
    float* __restrict__ out, float* __restrict__ stdo) {

    // smem reused across phases: A-frags (32KB) -> z[256][72] f32 (73.7KB)
    // -> heads partials (16KB). Barriers separate the lifetimes.
    __shared__ __align__(16) char smem[73728];
    __shared__ float psum[4][64];
    __shared__ int   leafbuf[64];
    __shared__ float psbuf[64];

    const int tid  = threadIdx.x;
    const int wave = tid >> 6;
    const int lane = tid & 63;
    const int rowbase = blockIdx.x * ROWS_PB;

    s8v* Ah = (s8v*)smem;                 // [(ks*4+mt)*64 + lane]
    s8v* Al = (s8v*)(smem + 16384);
    float* zl = (float*)smem;             // z[n*72 + m] after MFMA phase

    // ---- phase 1: x block -> bf16 hi/lo A-fragments in LDS ----
    {
        const int r = lane, s = wave;     // row r, k-step s (32 wide)
        const float* xp = x + (size_t)(rowbase + r) * IN_DIM + s * 32;
        float f[32];
#pragma unroll
        for (int i = 0; i < 32; i += 4) {
            float4 v = *reinterpret_cast<const float4*>(xp + i);
            f[i] = v.x; f[i + 1] = v.y; f[i + 2] = v.z; f[i + 3] = v.w;
        }
        const int mt = r >> 4;
#pragma unroll
        for (int q = 0; q < 4; ++q) {
            s8v hi, lo;
#pragma unroll
            for (int j = 0; j < 8; ++j) {
                float v = f[q * 8 + j];
                unsigned short h = bfhi(v);
                hi[j] = (short)h;
                lo[j] = (short)bfhi(v - bf2f(h));
            }
            int slot = (s * 4 + mt) * 64 + ((r & 15) + 16 * q);
            Ah[slot] = hi;
            Al[slot] = lo;
        }
    }
    __syncthreads();

    // ---- phase 2: MFMA. z = xh*wh + xh*wl + xl*wh (fp32 acc). ----
    // Wave w owns node cols [64w, 64w+64): 4x4 tiles of 16x16.
    f4v acc[4][4];
#pragma unroll
    for (int mt = 0; mt < 4; ++mt)
#pragma unroll
        for (int nt = 0; nt < 4; ++nt)
            acc[mt][nt] = (f4v){0.f, 0.f, 0.f, 0.f};

    const s8v* Bh8 = (const s8v*)Bhg;
    const s8v* Bl8 = (const s8v*)Blg;
#pragma unroll
    for (int ks = 0; ks < 4; ++ks) {
        s8v ah[4], al[4], bh[4], bl[4];
#pragma unroll
        for (int mt = 0; mt < 4; ++mt) {
            ah[mt] = Ah[(ks * 4 + mt) * 64 + lane];
            al[mt] = Al[(ks * 4 + mt) * 64 + lane];
        }
#pragma unroll
        for (int nt = 0; nt < 4; ++nt) {
            int idx = (ks * 16 + (wave * 4 + nt)) * 64 + lane;  // L2-hot, coalesced
            bh[nt] = Bh8[idx];
            bl[nt] = Bl8[idx];
        }
#pragma unroll
        for (int mt = 0; mt < 4; ++mt)
#pragma unroll
            for (int nt = 0; nt < 4; ++nt) {
                acc[mt][nt] = __builtin_amdgcn_mfma_f32_16x16x32_bf16(ah[mt], bh[nt], acc[mt][nt], 0, 0, 0);
                acc[mt][nt] = __builtin_amdgcn_mfma_f32_16x16x32_bf16(ah[mt], bl[nt], acc[mt][nt], 0, 0, 0);
                acc[mt][nt] = __builtin_amdgcn_mfma_f32_16x16x32_bf16(al[mt], bh[nt], acc[mt][nt], 0, 0, 0);
            }
    }
    __syncthreads();   // A-frags dead; region becomes z

    // ---- phase 3: C/D -> LDS z[n][m] (stride 72 breaks pow2 conflicts) ----
    // C/D layout (m89): col n = lane&15, row m = (lane>>4)*4 + reg.
#pragma unroll
    for (int mt = 0; mt < 4; ++mt)
#pragma unroll
        for (int nt = 0; nt < 4; ++nt) {
            int n = (wave * 4 + nt) * 16 + (lane & 15);
            int m0 = mt * 16 + (lane >> 4) * 4;
            *reinterpret_cast<f4v*>(&zl[n * 72 + m0]) = acc[mt][nt];
        }
    __syncthreads();

    // ---- phase 4: |z + bp| partial sums; thread = (row r, node chunk c) ----
    {
        const int r = lane, c = wave;
        float s = 0.f;
#pragma unroll 4
        for (int i = 0; i < 64; ++i) {
            int n = c * 64 + i;
            if (n < INT_NODES)
                s += fabsf(zl[n * 72 + r] + bp[n]);
        }
        psum[c][r] = s;
    }
    __syncthreads();

    // ---- phase 5: hard traversal + closed-form p* (wave 0) ----
    if (wave == 0) {
        const int r = lane;
        float abs_sum = psum[0][r] + psum[1][r] + psum[2][r] + psum[3][r];
        int node = 0;
#pragma unroll
        for (int d = 0; d < 8; ++d) {
            float zv = zl[node * 72 + r] + bp[node];
            if (fabsf(zv) < 5e-4f) {     // rare: exact sign via fp64 from global
                double zd = (double)bp[node];
                const float* wr = Wp + node * IN_DIM;
                const float* xrow = x + (size_t)(rowbase + r) * IN_DIM;
                for (int k = 0; k < IN_DIM; ++k)
                    zd = fma((double)wr[k], (double)xrow[k], zd);
                zv = (zd < 0.0) ? -1.f : 1.f;
            }
            node = 2 * node + 1 + (zv < 0.f ? 1 : 0);
        }
        const float fac = abs_sum * (1.0f / (float)INT_NODES);
        // p* of argmax leaf: sum_l exp(and_z_l - 8 fac) = (1 + e^{-2 fac})^8.
        const float e = expf(-2.0f * fac);
        const float q = 1.0f + e;
        const float q2 = q * q, q4 = q2 * q2, q8 = q4 * q4;
        leafbuf[r] = node - INT_NODES;
        psbuf[r] = 1.0f / q8;
    }
    __syncthreads();

    // ---- phase 6: fp32 heads, K-split (same numerics as R4) ----
    float* hb = (float*)smem;   // [p][o][seg][row] = ((p*8+o)*4+sg)*64 + r
    {
        const int r = lane, sg = wave;
        const float* xp = x + (size_t)(rowbase + r) * IN_DIM + sg * 32;
        float xr[32];
#pragma unroll
        for (int i = 0; i < 32; i += 4) {
            float4 v = *reinterpret_cast<const float4*>(xp + i);
            xr[i] = v.x; xr[i + 1] = v.y; xr[i + 2] = v.z; xr[i + 3] = v.w;
        }
        const int leaf = leafbuf[r];
        const float* wl = Wor_t + (size_t)leaf * (OUT_DIM * IN_DIM) + sg * 32;
        const float* bb = bor + sg * 32;
#pragma unroll
        for (int o = 0; o < OUT_DIM; ++o) {
            const float* wo = wl + o * IN_DIM;
            const float* bo = bb + o * IN_DIM;
            float s0 = 0.f, s1 = 0.f, s2 = 0.f, s3 = 0.f;
            float b0 = 0.f, b1 = 0.f, b2 = 0.f, b3 = 0.f;
#pragma unroll
            for (int c2 = 0; c2 < 32; c2 += 4) {
                float4 wv = *reinterpret_cast<const float4*>(wo + c2);
                s0 = fmaf(wv.x, xr[c2 + 0], s0);
                s1 = fmaf(wv.y, xr[c2 + 1], s1);
                s2 = fmaf(wv.z, xr[c2 + 2], s2);
                s3 = fmaf(wv.w, xr[c2 + 3], s3);
                b0 = fmaf(bo[c2 + 0], xr[c2 + 0], b0);
                b1 = fmaf(bo[c2 + 1], xr[c2 + 1], b1);
                b2 = fmaf(bo[c2 + 2], xr[c2 + 2], b2);
                b3 = fmaf(bo[c2 + 3], xr[c2 + 3], b3);
            }
            hb[((0 * 8 + o) * 4 + sg) * 64 + r] = (s0 + s1) + (s2 + s3);
            hb[((1 * 8 + o) * 4 + sg) * 64 + r] = (b0 + b1) + (b2 + b3);
        }
    }
    __syncthreads();

    // ---- phase 7: final reduce + stores (2 outputs/thread) ----
    {
        const int r = tid & 63;
        const int og = tid >> 6;
        const float ps = psbuf[r];
        const int lf = leafbuf[r];
#pragma unroll
        for (int u = 0; u < 2; ++u) {
            const int o = og * 2 + u;
            float s = hb[((0 * 8 + o) * 4 + 0) * 64 + r] + hb[((0 * 8 + o) * 4 + 1) * 64 + r]
                    + hb[((0 * 8 + o) * 4 + 2) * 64 + r] + hb[((0 * 8 + o) * 4 + 3) * 64 + r];
            float b = hb[((1 * 8 + o) * 4 + 0) * 64 + r] + hb[((1 * 8 + o) * 4 + 1) * 64 + r]
                    + hb[((1 * 8 + o) * 4 + 2) * 64 + r] + hb[((1 * 8 + o) * 4 + 3) * 64 + r];
            out[(size_t)(rowbase + r) * OUT_DIM + o] = ps * s + b;
            float sd = ps * stds[lf * OUT_DIM + o];
            stdo[(size_t)(rowbase + r) * OUT_DIM + o] = fminf(fmaxf(sd, -20.0f), 2.0f);
        }
    }
}

extern "C" void kernel_launch(void* const* d_in, const int* in_sizes, int n_in,
                              void* d_out, int out_size, void* d_ws, size_t ws_size,
                              hipStream_t stream) {
    const float* x    = (const float*)d_in[0];
    const float* Wp   = (const float*)d_in[1];
    const float* bp   = (const float*)d_in[2];
    // d_in[3] = Wand -- folded into the traversal, unused.
    const float* Wor  = (const float*)d_in[4];
    const float* bor  = (const float*)d_in[5];
    const float* stds = (const float*)d_in[6];
    float* out = (float*)d_out;

    float* wor_t = (float*)d_ws;                                   // 1 MB
    unsigned short* Bh = (unsigned short*)((char*)d_ws + (1 << 20));          // 64 KB
    unsigned short* Bl = (unsigned short*)((char*)d_ws + (1 << 20) + (64 << 10)); // 64 KB

    transpose_wor<<<(LEAF * OUT_DIM * IN_DIM) / 256, 256, 0, stream>>>(Wor, wor_t);
    build_bfrag<<<128, 256, 0, stream>>>(Wp, Bh, Bl);
    dgt_main<<<NBLK, 256, 0, stream>>>(x, Wp, bp, Bh, Bl, wor_t, bor, stds,
                                       out, out + (size_t)BATCH * OUT_DIM);
}